// Round 8
// baseline (348.289 us; speedup 1.0000x reference)
//
#include <hip/hip_runtime.h>
#include <hip/hip_bf16.h>

#define TSEQ 2048
#define NBATCH 8
#define NROWS (NBATCH*TSEQ)   // 16384
#define EMB 128
#define NH 4
#define DH 32
#define OUTD 32
#define APLANE (NROWS*EMB)
#define LOG2E 1.4426950408889634f

typedef short s8v __attribute__((ext_vector_type(8)));
typedef short s4v __attribute__((ext_vector_type(4)));
typedef float f4v __attribute__((ext_vector_type(4)));

__device__ __forceinline__ unsigned short f2bf(float f){
  unsigned int u = __float_as_uint(f);
  unsigned int r = u + 0x7fffu + ((u >> 16) & 1u);
  return (unsigned short)(r >> 16);
}
__device__ __forceinline__ float bf2f(unsigned short u){
  return __uint_as_float(((unsigned int)u) << 16);
}

// ---------------- weight prep ----------------
struct WPack {
  const float* src[10];
  int off[10];
  int ntk[10];
  int rowoff[10];
  int nsh[10];
  int kn[10];
};
__global__ __launch_bounds__(256) void prep_w(WPack p, short* __restrict__ warena){
  int blk = blockIdx.x, m = 0;
  #pragma unroll
  for (int i=0;i<10;i++){
    int nb = p.kn[i] >> 8;
    if (blk < nb){ m = i; break; }
    blk -= nb;
  }
  int idx = blk*256 + threadIdx.x;
  float x = p.src[m][idx];
  int nsh = p.nsh[m];
  int n = idx & ((1<<nsh)-1);
  int k = idx >> nsh;
  int K = p.kn[m] >> nsh;
  unsigned short hi = f2bf(x);
  unsigned short lo = f2bf(x - bf2f(hi));
  short* dh = warena + p.off[m] + (size_t)(p.rowoff[m] + n)*K + k;
  dh[0]        = (short)hi;
  dh[p.ntk[m]] = (short)lo;
}

// ---------------- fold F2B + out head ----------------
__global__ __launch_bounds__(256) void prep_wc(const float* __restrict__ f2W, const float* __restrict__ f2b,
                                               const float* __restrict__ oW, const float* __restrict__ ob,
                                               float* __restrict__ Wc, float* __restrict__ bc){
  int idx = blockIdx.x*256 + threadIdx.x;
  if (idx < 512*32){
    int k = idx >> 5, n = idx & 31;
    float s = 0.f;
    #pragma unroll 4
    for (int j=0;j<128;j++) s = fmaf(f2W[k*128+j], oW[j*32+n], s);
    Wc[idx] = s;
  } else if (idx < 512*32 + 32){
    int n = idx - 512*32;
    float s = ob[n];
    for (int j=0;j<128;j++) s = fmaf(f2b[j], oW[j*32+n], s);
    bc[n] = s;
  }
}

// ---------------- X split ----------------
__global__ __launch_bounds__(256) void xsplit(const float* __restrict__ kq, const float* __restrict__ v,
                                              unsigned short* __restrict__ X){
  int idx = blockIdx.x*256 + threadIdx.x;
  int row = idx >> 7, c = idx & 127;
  float val = (c < 64) ? kq[row*64 + c] : v[row*64 + (c-64)];
  unsigned short hi = f2bf(val);
  X[idx]          = hi;
  X[idx + APLANE] = f2bf(val - bf2f(hi));
}

// ---------------- pipelined MFMA GEMM ----------------
struct GOuts {
  const float* bias[3];
  float* of[3];
  unsigned short* ob[3];
  float scale[3];
};
__global__ __launch_bounds__(256) void gemm2(
    const unsigned short* __restrict__ A, int aplane, int lda, int K, int niter,
    const short* __restrict__ wt, int NTK,
    GOuts og, int NT, int nseg, int act){
  __shared__ short As[2][2][64*40];
  const int tid  = threadIdx.x;
  const int w    = tid >> 6;
  const int lane = tid & 63;
  const int col  = lane & 15;
  const int quad = lane >> 4;
  const int row0 = blockIdx.x * 64;
  const int colg = blockIdx.y*64 + w*16 + col;
  const bool two = (aplane != 0);

  f4v acc[4];
  #pragma unroll
  for (int i=0;i<4;i++) acc[i] = (f4v){0.f,0.f,0.f,0.f};

  const int ar = tid >> 2, ac = (tid & 3)*8;
  const unsigned short* abase = A + (size_t)(row0 + ar)*lda;
  const short* wbase = wt + (size_t)colg*K + quad*8;

  s8v pah, pal, pbh, pbl;
  pah = *(const s8v*)(abase + ac);
  if (two) pal = *(const s8v*)(abase + aplane + ac);
  pbh = *(const s8v*)(wbase);
  pbl = *(const s8v*)(wbase + NTK);

  for (int i=0;i<niter;i++){
    const int buf = i & 1;
    *(s8v*)&As[buf][0][ar*40 + ac] = pah;
    if (two) *(s8v*)&As[buf][1][ar*40 + ac] = pal;
    __syncthreads();
    s8v bh = pbh, bl = pbl;
    if (i+1 < niter){
      const int kcol = (i+1)*32;
      pah = *(const s8v*)(abase + kcol + ac);
      if (two) pal = *(const s8v*)(abase + aplane + kcol + ac);
      pbh = *(const s8v*)(wbase + kcol);
      pbl = *(const s8v*)(wbase + NTK + kcol);
    }
    #pragma unroll
    for (int rt=0;rt<4;rt++){
      s8v ah = *(const s8v*)&As[buf][0][(rt*16 + col)*40 + quad*8];
      acc[rt] = __builtin_amdgcn_mfma_f32_16x16x32_bf16(ah, bh, acc[rt], 0, 0, 0);
      if (two){
        s8v al = *(const s8v*)&As[buf][1][(rt*16 + col)*40 + quad*8];
        acc[rt] = __builtin_amdgcn_mfma_f32_16x16x32_bf16(al, bh, acc[rt], 0, 0, 0);
      }
      acc[rt] = __builtin_amdgcn_mfma_f32_16x16x32_bf16(ah, bl, acc[rt], 0, 0, 0);
    }
  }

  int seg, lcol, ldc;
  if (nseg > 1){ seg = colg >> 7; lcol = colg & 127; ldc = 128; }
  else         { seg = 0; lcol = colg; ldc = NT; }
  const float bv = og.bias[seg][lcol];
  const float sc = og.scale[seg];
  float* of = og.of[seg];
  unsigned short* ob = og.ob[seg];
  #pragma unroll
  for (int rt=0;rt<4;rt++){
    #pragma unroll
    for (int r=0;r<4;r++){
      const int row = row0 + rt*16 + quad*4 + r;
      float val = acc[rt][r] + bv;
      if (act == 1) val = 0.5f*val*(1.f + erff(val*0.70710678118654752440f));
      val *= sc;
      if (ob) ob[(size_t)row*ldc + lcol] = f2bf(val);
      if (of) of[(size_t)row*ldc + lcol] = val;
    }
  }
}

// ---------------- V transpose (bf16 in): Vbf [NROWS x 128] -> Vtb [32 bh][32 d][2048 t] ----------------
__global__ __launch_bounds__(256) void vtrans2(const unsigned short* __restrict__ Vbf,
                                               unsigned short* __restrict__ Vtb){
  __shared__ short Lt[64*40];
  const int tid = threadIdx.x;
  const int t0 = blockIdx.x * 64;
  const int bh = blockIdx.y;
  const int b = bh >> 2, h = bh & 3;
  {
    const int r = tid >> 2, c = (tid & 3)*8;
    *(s8v*)&Lt[r*40 + c] = *(const s8v*)(Vbf + (size_t)(b*TSEQ + t0 + r)*EMB + h*DH + c);
  }
  __syncthreads();
  const int d = tid >> 3, kc = (tid & 7)*8;
  s8v o;
  #pragma unroll
  for (int j=0;j<8;j++) o[j] = Lt[(kc + j)*40 + d];
  *(s8v*)(Vtb + ((size_t)bh*32 + d)*TSEQ + t0 + kc) = o;
}

// ---------------- merged-pass 4-way split-K MFMA flash attention ----------------
// Block handles q-tiles tA=63-bx (heavy) and tB=bx; keys(tB) subset of keys(tA) -> shared staging.
// Parity z in {0..3} takes jt = z, z+4, ...  Unnormalized partials into O[z], L[z].
#define KT_STRIDE 40
#define VT_STRIDE 72
#define PW_STRIDE 72
__global__ __launch_bounds__(128) void flash4(const unsigned short* __restrict__ Qb,
                                              const unsigned short* __restrict__ Kb,
                                              const unsigned short* __restrict__ Vtb,
                                              float* __restrict__ O0, float* __restrict__ O1,
                                              float* __restrict__ O2, float* __restrict__ O3,
                                              float* __restrict__ L0, float* __restrict__ L1,
                                              float* __restrict__ L2, float* __restrict__ L3,
                                              int mode){
  __shared__ short Kt[64*KT_STRIDE];
  __shared__ short Vt[32*VT_STRIDE];
  __shared__ short Pw[2][16*PW_STRIDE];
  const int tid  = threadIdx.x;
  const int w    = tid >> 6;
  const int lane = tid & 63;
  const int col  = lane & 15;
  const int quad = lane >> 4;
  const int bh = blockIdx.y;
  const int b = bh >> 2, h = bh & 3;
  const int par = blockIdx.z;
  float* Op = (par==0) ? O0 : (par==1) ? O1 : (par==2) ? O2 : O3;
  float* Lp = (par==0) ? L0 : (par==1) ? L1 : (par==2) ? L2 : L3;
  const int kr = tid >> 1, kc16 = (tid & 1)*16;
  const int vd = tid >> 2, vk16 = (tid & 3)*16;

  const int tA = 63 - blockIdx.x, tB = blockIdx.x;
  const int jtA = tA >> 1, jtB = tB >> 1;          // jtB <= 15 < 16 <= jtA
  const int qA = tA*32 + w*16 + col;
  const int qB = tB*32 + w*16 + col;

  s8v qfA = *(const s8v*)(Qb + (size_t)(b*TSEQ + qA)*EMB + h*DH + quad*8);
  s8v qfB = *(const s8v*)(Qb + (size_t)(b*TSEQ + qB)*EMB + h*DH + quad*8);
  f4v oA0 = {0,0,0,0}, oA1 = {0,0,0,0}, oB0 = {0,0,0,0}, oB1 = {0,0,0,0};
  float lsA = 0.f, lsB = 0.f;

  s8v ka, kb2, va, vb;
  {
    const unsigned short* kp = Kb + (size_t)(b*TSEQ + par*64 + kr)*EMB + h*DH + kc16;
    ka = *(const s8v*)kp; kb2 = *(const s8v*)(kp + 8);
    const unsigned short* vp = Vtb + ((size_t)bh*32 + vd)*TSEQ + par*64 + vk16;
    va = *(const s8v*)vp; vb = *(const s8v*)(vp + 8);
  }

  for (int jt = par; jt <= jtA; jt += 4){
    __syncthreads();
    *(s8v*)&Kt[kr*KT_STRIDE + kc16]     = ka;
    *(s8v*)&Kt[kr*KT_STRIDE + kc16 + 8] = kb2;
    *(s8v*)&Vt[vd*VT_STRIDE + vk16]     = va;
    *(s8v*)&Vt[vd*VT_STRIDE + vk16 + 8] = vb;
    __syncthreads();
    if (jt + 4 <= jtA){
      const unsigned short* kp = Kb + (size_t)(b*TSEQ + (jt+4)*64 + kr)*EMB + h*DH + kc16;
      ka = *(const s8v*)kp; kb2 = *(const s8v*)(kp + 8);
      const unsigned short* vp = Vtb + ((size_t)bh*32 + vd)*TSEQ + (jt+4)*64 + vk16;
      va = *(const s8v*)vp; vb = *(const s8v*)(vp + 8);
    }
    // V fragments once, reused by both tiles' PV
    s8v vr00 = *(const s8v*)&Vt[(col)*VT_STRIDE + quad*8];
    s8v vr01 = *(const s8v*)&Vt[(16+col)*VT_STRIDE + quad*8];
    s8v vr10 = *(const s8v*)&Vt[(col)*VT_STRIDE + 32 + quad*8];
    s8v vr11 = *(const s8v*)&Vt[(16+col)*VT_STRIDE + 32 + quad*8];
    // K fragments
    s8v kf0 = *(const s8v*)&Kt[(col)*KT_STRIDE + quad*8];
    s8v kf1 = *(const s8v*)&Kt[(16+col)*KT_STRIDE + quad*8];
    s8v kf2 = *(const s8v*)&Kt[(32+col)*KT_STRIDE + quad*8];
    s8v kf3 = *(const s8v*)&Kt[(48+col)*KT_STRIDE + quad*8];

    // ---- tile A ----
    {
      f4v s[4];
      f4v z = {0,0,0,0};
      s[0] = __builtin_amdgcn_mfma_f32_16x16x32_bf16(kf0, qfA, z, 0, 0, 0);
      s[1] = __builtin_amdgcn_mfma_f32_16x16x32_bf16(kf1, qfA, z, 0, 0, 0);
      s[2] = __builtin_amdgcn_mfma_f32_16x16x32_bf16(kf2, qfA, z, 0, 0, 0);
      s[3] = __builtin_amdgcn_mfma_f32_16x16x32_bf16(kf3, qfA, z, 0, 0, 0);
      if (jt == jtA){
        const int j0 = jt*64;
        #pragma unroll
        for (int t4=0;t4<4;t4++){
          #pragma unroll
          for (int r=0;r<4;r++){
            const int jg = j0 + t4*16 + quad*4 + r;
            const bool ok = (mode==0) ? (jg <= qA) : ((jg < qA) || (qA==0 && jg==0));
            s[t4][r] = ok ? s[t4][r] : -1e30f;
          }
        }
      }
      #pragma unroll
      for (int t4=0;t4<4;t4++){
        s4v pk;
        #pragma unroll
        for (int r=0;r<4;r++){
          float pv = exp2f(s[t4][r]);
          lsA += pv;
          pk[r] = (short)f2bf(pv);
        }
        *(s4v*)&Pw[w][col*PW_STRIDE + t4*16 + quad*4] = pk;
      }
      s8v pf0 = *(const s8v*)&Pw[w][col*PW_STRIDE + quad*8];
      s8v pf1 = *(const s8v*)&Pw[w][col*PW_STRIDE + 32 + quad*8];
      oA0 = __builtin_amdgcn_mfma_f32_16x16x32_bf16(vr00, pf0, oA0, 0, 0, 0);
      oA1 = __builtin_amdgcn_mfma_f32_16x16x32_bf16(vr01, pf0, oA1, 0, 0, 0);
      oA0 = __builtin_amdgcn_mfma_f32_16x16x32_bf16(vr10, pf1, oA0, 0, 0, 0);
      oA1 = __builtin_amdgcn_mfma_f32_16x16x32_bf16(vr11, pf1, oA1, 0, 0, 0);
    }
    // ---- tile B (shares staged K/V) ----
    if (jt <= jtB){
      f4v s[4];
      f4v z = {0,0,0,0};
      s[0] = __builtin_amdgcn_mfma_f32_16x16x32_bf16(kf0, qfB, z, 0, 0, 0);
      s[1] = __builtin_amdgcn_mfma_f32_16x16x32_bf16(kf1, qfB, z, 0, 0, 0);
      s[2] = __builtin_amdgcn_mfma_f32_16x16x32_bf16(kf2, qfB, z, 0, 0, 0);
      s[3] = __builtin_amdgcn_mfma_f32_16x16x32_bf16(kf3, qfB, z, 0, 0, 0);
      if (jt == jtB){
        const int j0 = jt*64;
        #pragma unroll
        for (int t4=0;t4<4;t4++){
          #pragma unroll
          for (int r=0;r<4;r++){
            const int jg = j0 + t4*16 + quad*4 + r;
            const bool ok = (mode==0) ? (jg <= qB) : ((jg < qB) || (qB==0 && jg==0));
            s[t4][r] = ok ? s[t4][r] : -1e30f;
          }
        }
      }
      #pragma unroll
      for (int t4=0;t4<4;t4++){
        s4v pk;
        #pragma unroll
        for (int r=0;r<4;r++){
          float pv = exp2f(s[t4][r]);
          lsB += pv;
          pk[r] = (short)f2bf(pv);
        }
        *(s4v*)&Pw[w][col*PW_STRIDE + t4*16 + quad*4] = pk;
      }
      s8v pf0 = *(const s8v*)&Pw[w][col*PW_STRIDE + quad*8];
      s8v pf1 = *(const s8v*)&Pw[w][col*PW_STRIDE + 32 + quad*8];
      oB0 = __builtin_amdgcn_mfma_f32_16x16x32_bf16(vr00, pf0, oB0, 0, 0, 0);
      oB1 = __builtin_amdgcn_mfma_f32_16x16x32_bf16(vr01, pf0, oB1, 0, 0, 0);
      oB0 = __builtin_amdgcn_mfma_f32_16x16x32_bf16(vr10, pf1, oB0, 0, 0, 0);
      oB1 = __builtin_amdgcn_mfma_f32_16x16x32_bf16(vr11, pf1, oB1, 0, 0, 0);
    }
  }
  // ---- epilogue: both tiles ----
  lsA += __shfl_xor(lsA, 16); lsA += __shfl_xor(lsA, 32);
  lsB += __shfl_xor(lsB, 16); lsB += __shfl_xor(lsB, 32);
  float* oa = Op + (size_t)(b*TSEQ + qA)*EMB + h*DH + quad*4;
  *(float4*)(oa)      = make_float4(oA0[0],oA0[1],oA0[2],oA0[3]);
  *(float4*)(oa + 16) = make_float4(oA1[0],oA1[1],oA1[2],oA1[3]);
  float* obp = Op + (size_t)(b*TSEQ + qB)*EMB + h*DH + quad*4;
  *(float4*)(obp)      = make_float4(oB0[0],oB0[1],oB0[2],oB0[3]);
  *(float4*)(obp + 16) = make_float4(oB1[0],oB1[1],oB1[2],oB1[3]);
  if (quad == 0){
    Lp[(size_t)(b*TSEQ + qA)*NH + h] = lsA;
    Lp[(size_t)(b*TSEQ + qB)*NH + h] = lsB;
  }
}

// ---------------- combine(4) + residual + LN (layer A) -> dual-plane bf16 ----------------
__global__ __launch_bounds__(64) void combine_ln(const float* __restrict__ O0, const float* __restrict__ O1,
                                                 const float* __restrict__ O2, const float* __restrict__ O3,
                                                 const float* __restrict__ L0, const float* __restrict__ L1,
                                                 const float* __restrict__ L2, const float* __restrict__ L3,
                                                 const float* __restrict__ Vf,
                                                 const float* __restrict__ g, const float* __restrict__ bt,
                                                 unsigned short* __restrict__ outp){
  const int row = blockIdx.x;
  const int tid = threadIdx.x;
  const size_t base = (size_t)row*EMB;
  const int h0 = tid >> 5, h1i = 2 + (tid >> 5);
  const size_t lb0 = (size_t)row*NH;
  const float la = L0[lb0+h0] + L1[lb0+h0] + L2[lb0+h0] + L3[lb0+h0];
  const float lb = L0[lb0+h1i] + L1[lb0+h1i] + L2[lb0+h1i] + L3[lb0+h1i];
  float x0 = Vf[base+tid]    + (O0[base+tid]    + O1[base+tid]    + O2[base+tid]    + O3[base+tid])    / la;
  float x1 = Vf[base+tid+64] + (O0[base+tid+64] + O1[base+tid+64] + O2[base+tid+64] + O3[base+tid+64]) / lb;
  float s  = x0 + x1;
  float s2 = x0*x0 + x1*x1;
  #pragma unroll
  for (int off=1; off<64; off<<=1){
    s  += __shfl_xor(s,  off);
    s2 += __shfl_xor(s2, off);
  }
  float mean = s * (1.f/128.f);
  float var  = s2 * (1.f/128.f) - mean*mean;
  float rstd = rsqrtf(var + 1e-5f);
  float y0 = (x0-mean)*rstd*g[tid]    + bt[tid];
  float y1 = (x1-mean)*rstd*g[tid+64] + bt[tid+64];
  unsigned short h0b = f2bf(y0), h1b = f2bf(y1);
  outp[base+tid]             = h0b;
  outp[base+tid+64]          = h1b;
  outp[base+tid+APLANE]      = f2bf(y0 - bf2f(h0b));
  outp[base+tid+64+APLANE]   = f2bf(y1 - bf2f(h1b));
}

// ---------------- residual LN ----------------
__global__ __launch_bounds__(64) void ln2(const unsigned short* __restrict__ Xp, const float* __restrict__ R,
                                          const float* __restrict__ g, const float* __restrict__ bt,
                                          unsigned short* __restrict__ outp){
  const int row = blockIdx.x;
  const int tid = threadIdx.x;
  const size_t base = (size_t)row*EMB;
  float x0 = bf2f(Xp[base+tid])    + bf2f(Xp[base+tid+APLANE])    + R[base+tid];
  float x1 = bf2f(Xp[base+tid+64]) + bf2f(Xp[base+tid+64+APLANE]) + R[base+tid+64];
  float s  = x0 + x1;
  float s2 = x0*x0 + x1*x1;
  #pragma unroll
  for (int off=1; off<64; off<<=1){
    s  += __shfl_xor(s,  off);
    s2 += __shfl_xor(s2, off);
  }
  float mean = s * (1.f/128.f);
  float var  = s2 * (1.f/128.f) - mean*mean;
  float rstd = rsqrtf(var + 1e-5f);
  float y0 = (x0-mean)*rstd*g[tid]    + bt[tid];
  float y1 = (x1-mean)*rstd*g[tid+64] + bt[tid+64];
  unsigned short h0b = f2bf(y0), h1b = f2bf(y1);
  outp[base+tid]             = h0b;
  outp[base+tid+64]          = h1b;
  outp[base+tid+APLANE]      = f2bf(y0 - bf2f(h0b));
  outp[base+tid+64+APLANE]   = f2bf(y1 - bf2f(h1b));
}

// ---------------- combine(4) (layer B) -> dual-plane bf16 ----------------
__global__ __launch_bounds__(256) void combine_b(const float* __restrict__ O0, const float* __restrict__ O1,
                                                 const float* __restrict__ O2, const float* __restrict__ O3,
                                                 const float* __restrict__ L0, const float* __restrict__ L1,
                                                 const float* __restrict__ L2, const float* __restrict__ L3,
                                                 unsigned short* __restrict__ outp){
  const int idx = blockIdx.x*256 + threadIdx.x;
  const int row = idx >> 7, c = idx & 127, h = c >> 5;
  const size_t lb = (size_t)row*NH + h;
  const float l = L0[lb] + L1[lb] + L2[lb] + L3[lb];
  const float v = (O0[idx] + O1[idx] + O2[idx] + O3[idx]) / l;
  unsigned short hb = f2bf(v);
  outp[idx]          = hb;
  outp[idx + APLANE] = f2bf(v - bf2f(hb));
}

// ---------------- fused F2B+head ----------------
__global__ __launch_bounds__(256) void out2(const unsigned short* __restrict__ mid,
                                            const float* __restrict__ Wc, const float* __restrict__ bc,
                                            float* __restrict__ out){
  __shared__ float As[8*512];
  const int tid = threadIdx.x;
  const int row0 = blockIdx.x*8;
  for (int idx = tid; idx < 8*512; idx += 256)
    As[idx] = bf2f(mid[(size_t)row0*512 + idx]);
  __syncthreads();
  const int r = tid >> 5, c = tid & 31;
  float acc = bc[c];
  const float* as = &As[r*512];
  #pragma unroll 8
  for (int k=0;k<512;k++) acc = fmaf(as[k], Wc[k*32+c], acc);
  out[(size_t)(row0+r)*OUTD + c] = acc;
}

extern "C" void kernel_launch(void* const* d_in, const int* in_sizes, int n_in,
                              void* d_out, int out_size, void* d_ws, size_t ws_size,
                              hipStream_t stream) {
  const float* kq    = (const float*)d_in[0];
  const float* v     = (const float*)d_in[1];
  const float* A_Wk  = (const float*)d_in[2];  const float* A_bk  = (const float*)d_in[3];
  const float* A_Wq  = (const float*)d_in[4];  const float* A_bq  = (const float*)d_in[5];
  const float* A_Wv  = (const float*)d_in[6];  const float* A_bv  = (const float*)d_in[7];
  const float* A_f1W = (const float*)d_in[8];  const float* A_f1b = (const float*)d_in[9];
  const float* A_f2W = (const float*)d_in[10]; const float* A_f2b = (const float*)d_in[11];
  const float* A_n1g = (const float*)d_in[12]; const float* A_n1b = (const float*)d_in[13];
  const float* A_n2g = (const float*)d_in[14]; const float* A_n2b = (const float*)d_in[15];
  const float* B_Wk  = (const float*)d_in[16]; const float* B_bk  = (const float*)d_in[17];
  const float* B_Wq  = (const float*)d_in[18]; const float* B_bq  = (const float*)d_in[19];
  const float* B_Wv  = (const float*)d_in[20]; const float* B_bv  = (const float*)d_in[21];
  const float* B_f1W = (const float*)d_in[22]; const float* B_f1b = (const float*)d_in[23];
  const float* B_f2W = (const float*)d_in[24]; const float* B_f2b = (const float*)d_in[25];
  const float* out_W = (const float*)d_in[26]; const float* out_b = (const float*)d_in[27];
  float* out = (float*)d_out;
  (void)in_sizes; (void)n_in; (void)out_size; (void)ws_size;

  char* ws = (char*)d_ws;
  const size_t MB = 1024*1024;
  short* warena = (short*)ws;                              // 0-1.5 MB
  float* Wc  = (float*)(ws + 1536*1024);                   // 64 KB
  float* bc  = (float*)(ws + 1536*1024 + 65536);
  unsigned short* Xs  = (unsigned short*)(ws + 2*MB);      // 2-10
  unsigned short* Qbf = (unsigned short*)(ws + 10*MB);     // 10-14
  unsigned short* Kbf = (unsigned short*)(ws + 14*MB);     // 14-18
  unsigned short* Vtb = (unsigned short*)(ws + 18*MB);     // 18-22
  unsigned short* Vbf = (unsigned short*)(ws + 22*MB);     // 22-26
  float* Vf  = (float*)(ws + 26*MB);                       // 26-34 (layer A residual)
  float* O0  = (float*)(ws + 34*MB);                       // 34-42
  float* O1  = (float*)(ws + 42*MB);                       // 42-50
  float* O2  = (float*)(ws + 50*MB);                       // 50-58
  float* O3  = (float*)(ws + 58*MB);                       // 58-66
  float* L0  = (float*)(ws + 66*MB);
  float* L1  = (float*)(ws + 66*MB + 262144);
  float* L2  = (float*)(ws + 66*MB + 524288);
  float* L3  = (float*)(ws + 66*MB + 786432);
  unsigned short* h1p = (unsigned short*)(ws + 67*MB);     // 67-75
  // lifetime overlays (dead after their consumers; see journal):
  float* ffo = (float*)(ws + 34*MB);                       // overlays O0 (dead post-combine)
  unsigned short* vAp = (unsigned short*)(ws + 42*MB);     // overlays O1
  unsigned short* mid = (unsigned short*)(ws + 50*MB);     // overlays O2+O3

  // ---- weight prep ----
  WPack p;
  const float* srcs[10] = {A_Wq,A_Wk,A_Wv,A_f1W,A_f2W,B_Wq,B_Wk,B_Wv,B_f1W,B_f2W};
  int kn[10]     = {16384,16384,16384,65536,65536,8192,8192,16384,65536,65536};
  int nsh[10]    = {7,7,7,9,7,7,7,7,9,7};
  int off[10]    = {0,0,0,98304,229376,360448,360448,393216,425984,557056};
  int ntk[10]    = {49152,49152,49152,65536,65536,16384,16384,16384,65536,65536};
  int rowoff[10] = {0,128,256,0,0,0,128,0,0,0};
  int nblk = 0;
  for (int i=0;i<10;i++){
    p.src[i]=srcs[i]; p.kn[i]=kn[i]; p.nsh[i]=nsh[i];
    p.off[i]=off[i]; p.ntk[i]=ntk[i]; p.rowoff[i]=rowoff[i];
    nblk += kn[i] >> 8;
  }
  prep_w<<<nblk, 256, 0, stream>>>(p, warena);
  prep_wc<<<65, 256, 0, stream>>>(B_f2W, B_f2b, out_W, out_b, Wc, bc);
  xsplit<<<NROWS*128/256, 256, 0, stream>>>(kq, v, Xs);

  GOuts oQKVA = {{A_bq,A_bk,A_bv},{nullptr,nullptr,Vf},{Qbf,Kbf,Vbf},{LOG2E,1.f,1.f}};
  GOuts oF1A  = {{A_f1b,nullptr,nullptr},{nullptr,nullptr,nullptr},{mid,nullptr,nullptr},{1.f,1.f,1.f}};
  GOuts oF2A  = {{A_f2b,nullptr,nullptr},{ffo,nullptr,nullptr},{nullptr,nullptr,nullptr},{1.f,1.f,1.f}};
  GOuts oQKB  = {{B_bq,B_bk,nullptr},{nullptr,nullptr,nullptr},{Qbf,Kbf,nullptr},{LOG2E,1.f,1.f}};
  GOuts oVB   = {{B_bv,nullptr,nullptr},{nullptr,nullptr,nullptr},{Vbf,nullptr,nullptr},{1.f,1.f,1.f}};
  GOuts oF1B  = {{B_f1b,nullptr,nullptr},{nullptr,nullptr,nullptr},{mid,nullptr,nullptr},{1.f,1.f,1.f}};

  // ---- Layer A ----
  gemm2<<<dim3(256,6), 256, 0, stream>>>(Xs, APLANE, 128, 128, 4, warena + 0,      49152, oQKVA, 384, 3, 0);
  vtrans2<<<dim3(32,32), 256, 0, stream>>>(Vbf, Vtb);
  flash4<<<dim3(32,32,4), 128, 0, stream>>>(Qbf, Kbf, Vtb, O0,O1,O2,O3, L0,L1,L2,L3, 0);
  combine_ln<<<NROWS, 64, 0, stream>>>(O0,O1,O2,O3, L0,L1,L2,L3, Vf, A_n1g, A_n1b, h1p);
  gemm2<<<dim3(256,8), 256, 0, stream>>>(h1p, APLANE, 128, 128, 4, warena + 98304, 65536, oF1A, 512, 1, 1);
  gemm2<<<dim3(256,2), 256, 0, stream>>>(mid, 0,      512, 512, 16, warena + 229376, 65536, oF2A, 128, 1, 0);
  ln2<<<NROWS, 64, 0, stream>>>(h1p, ffo, A_n2g, A_n2b, vAp);

  // ---- Layer B ----
  gemm2<<<dim3(256,4), 256, 0, stream>>>(Xs, APLANE, 128, 64, 2,  warena + 360448, 16384, oQKB, 256, 2, 0);
  gemm2<<<dim3(256,2), 256, 0, stream>>>(vAp, APLANE, 128, 128, 4, warena + 393216, 16384, oVB, 128, 1, 0);
  vtrans2<<<dim3(32,32), 256, 0, stream>>>(Vbf, Vtb);
  flash4<<<dim3(32,32,4), 128, 0, stream>>>(Qbf, Kbf, Vtb, O0,O1,O2,O3, L0,L1,L2,L3, 1);
  combine_b<<<NROWS*128/256, 256, 0, stream>>>(O0,O1,O2,O3, L0,L1,L2,L3, h1p);
  gemm2<<<dim3(256,8), 256, 0, stream>>>(h1p, APLANE, 128, 128, 4, warena + 425984, 65536, oF1B, 512, 1, 1);
  out2<<<NROWS/8, 256, 0, stream>>>(mid, Wc, bc, out);
}

// Round 9
// 326.010 us; speedup vs baseline: 1.0683x; 1.0683x over previous
//
#include <hip/hip_runtime.h>
#include <hip/hip_bf16.h>

#define TSEQ 2048
#define NBATCH 8
#define NROWS (NBATCH*TSEQ)   // 16384
#define EMB 128
#define NH 4
#define DH 32
#define OUTD 32
#define APLANE (NROWS*EMB)
#define LOG2E 1.4426950408889634f

typedef short s8v __attribute__((ext_vector_type(8)));
typedef float f4v __attribute__((ext_vector_type(4)));

__device__ __forceinline__ unsigned short f2bf(float f){
  unsigned int u = __float_as_uint(f);
  unsigned int r = u + 0x7fffu + ((u >> 16) & 1u);
  return (unsigned short)(r >> 16);
}
__device__ __forceinline__ float bf2f(unsigned short u){
  return __uint_as_float(((unsigned int)u) << 16);
}

// ---------------- fused prep: weight split + Wc fold + X split ----------------
struct WPack {
  const float* src[10];
  int off[10];
  int ntk[10];
  int rowoff[10];
  int nsh[10];
  int kn[10];
};
struct PrepArgs {
  const float* f2W; const float* f2b; const float* oW; const float* ob;
  float* Wc; float* bc;
  const float* kq; const float* v;
  unsigned short* X;
  int nblk_w;
};
__global__ __launch_bounds__(256) void prep_all(WPack p, PrepArgs a, short* __restrict__ warena){
  int bid = blockIdx.x;
  if (bid < a.nblk_w){
    int blk = bid, m = 0;
    #pragma unroll
    for (int i=0;i<10;i++){
      int nb = p.kn[i] >> 8;
      if (blk < nb){ m = i; break; }
      blk -= nb;
    }
    int idx = blk*256 + threadIdx.x;
    float x = p.src[m][idx];
    int nsh = p.nsh[m];
    int n = idx & ((1<<nsh)-1);
    int k = idx >> nsh;
    int K = p.kn[m] >> nsh;
    unsigned short hi = f2bf(x);
    unsigned short lo = f2bf(x - bf2f(hi));
    short* dh = warena + p.off[m] + (size_t)(p.rowoff[m] + n)*K + k;
    dh[0]        = (short)hi;
    dh[p.ntk[m]] = (short)lo;
  } else if (bid < a.nblk_w + 65){
    int idx = (bid - a.nblk_w)*256 + threadIdx.x;
    if (idx < 512*32){
      int k = idx >> 5, n = idx & 31;
      float s = 0.f;
      #pragma unroll 4
      for (int j=0;j<128;j++) s = fmaf(a.f2W[k*128+j], a.oW[j*32+n], s);
      a.Wc[idx] = s;
    } else if (idx < 512*32 + 32){
      int n = idx - 512*32;
      float s = a.ob[n];
      for (int j=0;j<128;j++) s = fmaf(a.f2b[j], a.oW[j*32+n], s);
      a.bc[n] = s;
    }
  } else {
    int idx = (bid - a.nblk_w - 65)*256 + threadIdx.x;
    int row = idx >> 7, c = idx & 127;
    float val = (c < 64) ? a.kq[row*64 + c] : a.v[row*64 + (c-64)];
    unsigned short hi = f2bf(val);
    a.X[idx]          = hi;
    a.X[idx + APLANE] = f2bf(val - bf2f(hi));
  }
}

// ---------------- pipelined MFMA GEMM ----------------
struct GOuts {
  const float* bias[3];
  float* of[3];
  unsigned short* ob[3];
  float scale[3];
};
__global__ __launch_bounds__(256) void gemm2(
    const unsigned short* __restrict__ A, int aplane, int lda, int K, int niter,
    const short* __restrict__ wt, int NTK,
    GOuts og, int NT, int nseg, int act){
  __shared__ short As[2][2][64*40];
  const int tid  = threadIdx.x;
  const int w    = tid >> 6;
  const int lane = tid & 63;
  const int col  = lane & 15;
  const int quad = lane >> 4;
  const int row0 = blockIdx.x * 64;
  const int colg = blockIdx.y*64 + w*16 + col;
  const bool two = (aplane != 0);

  f4v acc[4];
  #pragma unroll
  for (int i=0;i<4;i++) acc[i] = (f4v){0.f,0.f,0.f,0.f};

  const int ar = tid >> 2, ac = (tid & 3)*8;
  const unsigned short* abase = A + (size_t)(row0 + ar)*lda;
  const short* wbase = wt + (size_t)colg*K + quad*8;

  s8v pah, pal, pbh, pbl;
  pah = *(const s8v*)(abase + ac);
  if (two) pal = *(const s8v*)(abase + aplane + ac);
  pbh = *(const s8v*)(wbase);
  pbl = *(const s8v*)(wbase + NTK);

  for (int i=0;i<niter;i++){
    const int buf = i & 1;
    *(s8v*)&As[buf][0][ar*40 + ac] = pah;
    if (two) *(s8v*)&As[buf][1][ar*40 + ac] = pal;
    __syncthreads();
    s8v bh = pbh, bl = pbl;
    if (i+1 < niter){
      const int kcol = (i+1)*32;
      pah = *(const s8v*)(abase + kcol + ac);
      if (two) pal = *(const s8v*)(abase + aplane + kcol + ac);
      pbh = *(const s8v*)(wbase + kcol);
      pbl = *(const s8v*)(wbase + NTK + kcol);
    }
    #pragma unroll
    for (int rt=0;rt<4;rt++){
      s8v ah = *(const s8v*)&As[buf][0][(rt*16 + col)*40 + quad*8];
      acc[rt] = __builtin_amdgcn_mfma_f32_16x16x32_bf16(ah, bh, acc[rt], 0, 0, 0);
      if (two){
        s8v al = *(const s8v*)&As[buf][1][(rt*16 + col)*40 + quad*8];
        acc[rt] = __builtin_amdgcn_mfma_f32_16x16x32_bf16(al, bh, acc[rt], 0, 0, 0);
      }
      acc[rt] = __builtin_amdgcn_mfma_f32_16x16x32_bf16(ah, bl, acc[rt], 0, 0, 0);
    }
  }

  int seg, lcol, ldc;
  if (nseg > 1){ seg = colg >> 7; lcol = colg & 127; ldc = 128; }
  else         { seg = 0; lcol = colg; ldc = NT; }
  const float bv = og.bias[seg][lcol];
  const float sc = og.scale[seg];
  float* of = og.of[seg];
  unsigned short* ob = og.ob[seg];
  #pragma unroll
  for (int rt=0;rt<4;rt++){
    #pragma unroll
    for (int r=0;r<4;r++){
      const int row = row0 + rt*16 + quad*4 + r;
      float val = acc[rt][r] + bv;
      if (act == 1) val = 0.5f*val*(1.f + erff(val*0.70710678118654752440f));
      val *= sc;
      if (ob) ob[(size_t)row*ldc + lcol] = f2bf(val);
      if (of) of[(size_t)row*ldc + lcol] = val;
    }
  }
}

// ---------------- V transpose (bf16): Vbf [NROWS x 128] -> Vtb [32 bh][32 d][2048 t] ----------------
__global__ __launch_bounds__(256) void vtrans2(const unsigned short* __restrict__ Vbf,
                                               unsigned short* __restrict__ Vtb){
  __shared__ short Lt[64*40];
  const int tid = threadIdx.x;
  const int t0 = blockIdx.x * 64;
  const int bh = blockIdx.y;
  const int b = bh >> 2, h = bh & 3;
  {
    const int r = tid >> 2, c = (tid & 3)*8;
    *(s8v*)&Lt[r*40 + c] = *(const s8v*)(Vbf + (size_t)(b*TSEQ + t0 + r)*EMB + h*DH + c);
  }
  __syncthreads();
  const int d = tid >> 3, kc = (tid & 7)*8;
  s8v o;
  #pragma unroll
  for (int j=0;j<8;j++) o[j] = Lt[(kc + j)*40 + d];
  *(s8v*)(Vtb + ((size_t)bh*32 + d)*TSEQ + t0 + kc) = o;
}

// ---------------- 2-way split-K MFMA flash attention (operand-swapped, packed cvt, l via ones-MFMA) ----------------
// Block 128 thr = 2 waves, 32 q. Paired q-tiles (63-bx heavy, then bx). Parity z: jt = z, z+2, ...
#define KT_STRIDE 40
#define VT_STRIDE 72
#define PW_STRIDE 72
__global__ __launch_bounds__(128) void flash5(const unsigned short* __restrict__ Qb,
                                              const unsigned short* __restrict__ Kb,
                                              const unsigned short* __restrict__ Vtb,
                                              float* __restrict__ O0, float* __restrict__ O1,
                                              float* __restrict__ L0, float* __restrict__ L1,
                                              int mode){
  __shared__ short Kt[64*KT_STRIDE];
  __shared__ short Vt[32*VT_STRIDE];
  __shared__ short Pw[2][16*PW_STRIDE];
  const int tid  = threadIdx.x;
  const int w    = tid >> 6;
  const int lane = tid & 63;
  const int col  = lane & 15;
  const int quad = lane >> 4;
  const int bh = blockIdx.y;
  const int b = bh >> 2, h = bh & 3;
  const int par = blockIdx.z;
  float* Op = par ? O1 : O0;
  float* Lp = par ? L1 : L0;
  const int kr = tid >> 1, kc16 = (tid & 1)*16;
  const int vd = tid >> 2, vk16 = (tid & 3)*16;
  s8v ones;
  #pragma unroll
  for (int j=0;j<8;j++) ones[j] = (short)0x3F80;   // bf16 1.0

  for (int pass = 0; pass < 2; pass++){
    const int t = pass ? blockIdx.x : (63 - blockIdx.x);   // heavy tile first
    const int qbase = t*32 + w*16;
    const int jtmax = t >> 1;
    const int qg = qbase + col;

    s8v qf = *(const s8v*)(Qb + (size_t)(b*TSEQ + qg)*EMB + h*DH + quad*8);
    f4v o0 = {0,0,0,0}, o1 = {0,0,0,0}, lacc = {0,0,0,0};

    if (par <= jtmax){
      s8v ka, kb2, va, vb;
      {
        const unsigned short* kp = Kb + (size_t)(b*TSEQ + par*64 + kr)*EMB + h*DH + kc16;
        ka = *(const s8v*)kp; kb2 = *(const s8v*)(kp + 8);
        const unsigned short* vp = Vtb + ((size_t)bh*32 + vd)*TSEQ + par*64 + vk16;
        va = *(const s8v*)vp; vb = *(const s8v*)(vp + 8);
      }
      for (int jt = par; jt <= jtmax; jt += 2){
        __syncthreads();
        *(s8v*)&Kt[kr*KT_STRIDE + kc16]     = ka;
        *(s8v*)&Kt[kr*KT_STRIDE + kc16 + 8] = kb2;
        *(s8v*)&Vt[vd*VT_STRIDE + vk16]     = va;
        *(s8v*)&Vt[vd*VT_STRIDE + vk16 + 8] = vb;
        __syncthreads();
        if (jt + 2 <= jtmax){
          const unsigned short* kp = Kb + (size_t)(b*TSEQ + (jt+2)*64 + kr)*EMB + h*DH + kc16;
          ka = *(const s8v*)kp; kb2 = *(const s8v*)(kp + 8);
          const unsigned short* vp = Vtb + ((size_t)bh*32 + vd)*TSEQ + (jt+2)*64 + vk16;
          va = *(const s8v*)vp; vb = *(const s8v*)(vp + 8);
        }
        // ---- S^T = K·Q^T ----
        f4v s[4];
        f4v z = {0,0,0,0};
        #pragma unroll
        for (int t4=0;t4<4;t4++){
          s8v kf = *(const s8v*)&Kt[(t4*16 + col)*KT_STRIDE + quad*8];
          s[t4] = __builtin_amdgcn_mfma_f32_16x16x32_bf16(kf, qf, z, 0, 0, 0);
        }
        // ---- causal mask (diagonal tile only) ----
        if (jt == jtmax){
          const int j0 = jt*64;
          #pragma unroll
          for (int t4=0;t4<4;t4++){
            #pragma unroll
            for (int r=0;r<4;r++){
              const int jg = j0 + t4*16 + quad*4 + r;
              const bool ok = (mode==0) ? (jg <= qg) : ((jg < qg) || (qg==0 && jg==0));
              s[t4][r] = ok ? s[t4][r] : -1e30f;
            }
          }
        }
        // ---- p = exp2(s); packed bf16 cvt; key-consecutive 8B store ----
        #pragma unroll
        for (int t4=0;t4<4;t4++){
          float p0 = exp2f(s[t4][0]);
          float p1 = exp2f(s[t4][1]);
          float p2 = exp2f(s[t4][2]);
          float p3 = exp2f(s[t4][3]);
          __hip_bfloat162 c01 = __float22bfloat162_rn(make_float2(p0, p1));
          __hip_bfloat162 c23 = __float22bfloat162_rn(make_float2(p2, p3));
          int2 pk;
          pk.x = *reinterpret_cast<int*>(&c01);
          pk.y = *reinterpret_cast<int*>(&c23);
          *(int2*)&Pw[w][col*PW_STRIDE + t4*16 + quad*4] = pk;
        }
        // ---- O^T = V^T·P^T ; l = ones·P^T (3rd MFMA, no VALU) ----
        #pragma unroll
        for (int kk=0;kk<2;kk++){
          s8v pf  = *(const s8v*)&Pw[w][col*PW_STRIDE + kk*32 + quad*8];
          s8v vf0 = *(const s8v*)&Vt[(col)*VT_STRIDE    + kk*32 + quad*8];
          s8v vf1 = *(const s8v*)&Vt[(16+col)*VT_STRIDE + kk*32 + quad*8];
          o0   = __builtin_amdgcn_mfma_f32_16x16x32_bf16(vf0, pf, o0, 0, 0, 0);
          o1   = __builtin_amdgcn_mfma_f32_16x16x32_bf16(vf1, pf, o1, 0, 0, 0);
          lacc = __builtin_amdgcn_mfma_f32_16x16x32_bf16(ones, pf, lacc, 0, 0, 0);
        }
      }
    }
    // ---- epilogue: O^T rows are d -> thread holds O[q=qg][quad*4..+3, +16]; l replicated over quads ----
    float* ob = Op + (size_t)(b*TSEQ + qg)*EMB + h*DH + quad*4;
    *(float4*)(ob)      = make_float4(o0[0],o0[1],o0[2],o0[3]);
    *(float4*)(ob + 16) = make_float4(o1[0],o1[1],o1[2],o1[3]);
    if (quad == 0) Lp[(size_t)(b*TSEQ + qg)*NH + h] = lacc[0];
  }
}

// ---------------- combine(2) + residual + LN (layer A) -> dual-plane bf16 ----------------
__global__ __launch_bounds__(64) void combine_ln(const float* __restrict__ O0, const float* __restrict__ O1,
                                                 const float* __restrict__ L0, const float* __restrict__ L1,
                                                 const float* __restrict__ Vf,
                                                 const float* __restrict__ g, const float* __restrict__ bt,
                                                 unsigned short* __restrict__ outp){
  const int row = blockIdx.x;
  const int tid = threadIdx.x;
  const size_t base = (size_t)row*EMB;
  const int h0 = tid >> 5, h1i = 2 + (tid >> 5);
  const size_t lb0 = (size_t)row*NH;
  const float la = L0[lb0+h0] + L1[lb0+h0];
  const float lb = L0[lb0+h1i] + L1[lb0+h1i];
  float x0 = Vf[base+tid]    + (O0[base+tid]    + O1[base+tid])    / la;
  float x1 = Vf[base+tid+64] + (O0[base+tid+64] + O1[base+tid+64]) / lb;
  float s  = x0 + x1;
  float s2 = x0*x0 + x1*x1;
  #pragma unroll
  for (int off=1; off<64; off<<=1){
    s  += __shfl_xor(s,  off);
    s2 += __shfl_xor(s2, off);
  }
  float mean = s * (1.f/128.f);
  float var  = s2 * (1.f/128.f) - mean*mean;
  float rstd = rsqrtf(var + 1e-5f);
  float y0 = (x0-mean)*rstd*g[tid]    + bt[tid];
  float y1 = (x1-mean)*rstd*g[tid+64] + bt[tid+64];
  unsigned short h0b = f2bf(y0), h1b = f2bf(y1);
  outp[base+tid]             = h0b;
  outp[base+tid+64]          = h1b;
  outp[base+tid+APLANE]      = f2bf(y0 - bf2f(h0b));
  outp[base+tid+64+APLANE]   = f2bf(y1 - bf2f(h1b));
}

// ---------------- residual LN ----------------
__global__ __launch_bounds__(64) void ln2(const unsigned short* __restrict__ Xp, const float* __restrict__ R,
                                          const float* __restrict__ g, const float* __restrict__ bt,
                                          unsigned short* __restrict__ outp){
  const int row = blockIdx.x;
  const int tid = threadIdx.x;
  const size_t base = (size_t)row*EMB;
  float x0 = bf2f(Xp[base+tid])    + bf2f(Xp[base+tid+APLANE])    + R[base+tid];
  float x1 = bf2f(Xp[base+tid+64]) + bf2f(Xp[base+tid+64+APLANE]) + R[base+tid+64];
  float s  = x0 + x1;
  float s2 = x0*x0 + x1*x1;
  #pragma unroll
  for (int off=1; off<64; off<<=1){
    s  += __shfl_xor(s,  off);
    s2 += __shfl_xor(s2, off);
  }
  float mean = s * (1.f/128.f);
  float var  = s2 * (1.f/128.f) - mean*mean;
  float rstd = rsqrtf(var + 1e-5f);
  float y0 = (x0-mean)*rstd*g[tid]    + bt[tid];
  float y1 = (x1-mean)*rstd*g[tid+64] + bt[tid+64];
  unsigned short h0b = f2bf(y0), h1b = f2bf(y1);
  outp[base+tid]             = h0b;
  outp[base+tid+64]          = h1b;
  outp[base+tid+APLANE]      = f2bf(y0 - bf2f(h0b));
  outp[base+tid+64+APLANE]   = f2bf(y1 - bf2f(h1b));
}

// ---------------- combine(2) (layer B) -> dual-plane bf16 ----------------
__global__ __launch_bounds__(256) void combine_b(const float* __restrict__ O0, const float* __restrict__ O1,
                                                 const float* __restrict__ L0, const float* __restrict__ L1,
                                                 unsigned short* __restrict__ outp){
  const int idx = blockIdx.x*256 + threadIdx.x;
  const int row = idx >> 7, c = idx & 127, h = c >> 5;
  const size_t lb = (size_t)row*NH + h;
  const float l = L0[lb] + L1[lb];
  const float v = (O0[idx] + O1[idx]) / l;
  unsigned short hb = f2bf(v);
  outp[idx]          = hb;
  outp[idx + APLANE] = f2bf(v - bf2f(hb));
}

// ---------------- fused F2B+head ----------------
__global__ __launch_bounds__(256) void out2(const unsigned short* __restrict__ mid,
                                            const float* __restrict__ Wc, const float* __restrict__ bc,
                                            float* __restrict__ out){
  __shared__ float As[8*512];
  const int tid = threadIdx.x;
  const int row0 = blockIdx.x*8;
  for (int idx = tid; idx < 8*512; idx += 256)
    As[idx] = bf2f(mid[(size_t)row0*512 + idx]);
  __syncthreads();
  const int r = tid >> 5, c = tid & 31;
  float acc = bc[c];
  const float* as = &As[r*512];
  #pragma unroll 8
  for (int k=0;k<512;k++) acc = fmaf(as[k], Wc[k*32+c], acc);
  out[(size_t)(row0+r)*OUTD + c] = acc;
}

extern "C" void kernel_launch(void* const* d_in, const int* in_sizes, int n_in,
                              void* d_out, int out_size, void* d_ws, size_t ws_size,
                              hipStream_t stream) {
  const float* kq    = (const float*)d_in[0];
  const float* v     = (const float*)d_in[1];
  const float* A_Wk  = (const float*)d_in[2];  const float* A_bk  = (const float*)d_in[3];
  const float* A_Wq  = (const float*)d_in[4];  const float* A_bq  = (const float*)d_in[5];
  const float* A_Wv  = (const float*)d_in[6];  const float* A_bv  = (const float*)d_in[7];
  const float* A_f1W = (const float*)d_in[8];  const float* A_f1b = (const float*)d_in[9];
  const float* A_f2W = (const float*)d_in[10]; const float* A_f2b = (const float*)d_in[11];
  const float* A_n1g = (const float*)d_in[12]; const float* A_n1b = (const float*)d_in[13];
  const float* A_n2g = (const float*)d_in[14]; const float* A_n2b = (const float*)d_in[15];
  const float* B_Wk  = (const float*)d_in[16]; const float* B_bk  = (const float*)d_in[17];
  const float* B_Wq  = (const float*)d_in[18]; const float* B_bq  = (const float*)d_in[19];
  const float* B_Wv  = (const float*)d_in[20]; const float* B_bv  = (const float*)d_in[21];
  const float* B_f1W = (const float*)d_in[22]; const float* B_f1b = (const float*)d_in[23];
  const float* B_f2W = (const float*)d_in[24]; const float* B_f2b = (const float*)d_in[25];
  const float* out_W = (const float*)d_in[26]; const float* out_b = (const float*)d_in[27];
  float* out = (float*)d_out;
  (void)in_sizes; (void)n_in; (void)out_size; (void)ws_size;

  char* ws = (char*)d_ws;
  const size_t MB = 1024*1024;
  short* warena = (short*)ws;                              // 0-1.35 MB
  float* Wc  = (float*)(ws + 1536*1024);                   // 64 KB
  float* bc  = (float*)(ws + 1536*1024 + 65536);
  unsigned short* Xs  = (unsigned short*)(ws + 2*MB);      // 2-10
  unsigned short* Qbf = (unsigned short*)(ws + 10*MB);     // 10-14
  unsigned short* Kbf = (unsigned short*)(ws + 14*MB);     // 14-18
  unsigned short* Vtb = (unsigned short*)(ws + 18*MB);     // 18-22
  unsigned short* Vbf = (unsigned short*)(ws + 22*MB);     // 22-26
  float* Vf  = (float*)(ws + 26*MB);                       // 26-34 (layer A residual)
  float* O0  = (float*)(ws + 34*MB);                       // 34-42
  float* O1  = (float*)(ws + 42*MB);                       // 42-50
  float* L0  = (float*)(ws + 50*MB);                       // 256 KB
  float* L1  = (float*)(ws + 50*MB + 262144);
  unsigned short* h1p = (unsigned short*)(ws + 51*MB);     // 51-59: h1 / attnB dual-plane
  unsigned short* mid = (unsigned short*)(ws + 59*MB);     // 59-75: bf16 [N x 512]
  // lifetime overlays (dead before flash B writes O0/O1):
  float* ffo = (float*)(ws + 34*MB);                       // overlays O0
  unsigned short* vAp = (unsigned short*)(ws + 42*MB);     // overlays O1

  // ---- fused prep ----
  WPack p;
  const float* srcs[10] = {A_Wq,A_Wk,A_Wv,A_f1W,A_f2W,B_Wq,B_Wk,B_Wv,B_f1W,B_f2W};
  int kn[10]     = {16384,16384,16384,65536,65536,8192,8192,16384,65536,65536};
  int nsh[10]    = {7,7,7,9,7,7,7,7,9,7};
  int off[10]    = {0,0,0,98304,229376,360448,360448,393216,425984,557056};
  int ntk[10]    = {49152,49152,49152,65536,65536,16384,16384,16384,65536,65536};
  int rowoff[10] = {0,128,256,0,0,0,128,0,0,0};
  int nblk_w = 0;
  for (int i=0;i<10;i++){
    p.src[i]=srcs[i]; p.kn[i]=kn[i]; p.nsh[i]=nsh[i];
    p.off[i]=off[i]; p.ntk[i]=ntk[i]; p.rowoff[i]=rowoff[i];
    nblk_w += kn[i] >> 8;
  }
  PrepArgs pa;
  pa.f2W = B_f2W; pa.f2b = B_f2b; pa.oW = out_W; pa.ob = out_b;
  pa.Wc = Wc; pa.bc = bc; pa.kq = kq; pa.v = v; pa.X = Xs; pa.nblk_w = nblk_w;
  prep_all<<<nblk_w + 65 + NROWS*128/256, 256, 0, stream>>>(p, pa, warena);

  GOuts oQKVA = {{A_bq,A_bk,A_bv},{nullptr,nullptr,Vf},{Qbf,Kbf,Vbf},{LOG2E,1.f,1.f}};
  GOuts oF1A  = {{A_f1b,nullptr,nullptr},{nullptr,nullptr,nullptr},{mid,nullptr,nullptr},{1.f,1.f,1.f}};
  GOuts oF2A  = {{A_f2b,nullptr,nullptr},{ffo,nullptr,nullptr},{nullptr,nullptr,nullptr},{1.f,1.f,1.f}};
  GOuts oQKB  = {{B_bq,B_bk,nullptr},{nullptr,nullptr,nullptr},{Qbf,Kbf,nullptr},{LOG2E,1.f,1.f}};
  GOuts oVB   = {{B_bv,nullptr,nullptr},{nullptr,nullptr,nullptr},{Vbf,nullptr,nullptr},{1.f,1.f,1.f}};
  GOuts oF1B  = {{B_f1b,nullptr,nullptr},{nullptr,nullptr,nullptr},{mid,nullptr,nullptr},{1.f,1.f,1.f}};

  // ---- Layer A ----
  gemm2<<<dim3(256,6), 256, 0, stream>>>(Xs, APLANE, 128, 128, 4, warena + 0,      49152, oQKVA, 384, 3, 0);
  vtrans2<<<dim3(32,32), 256, 0, stream>>>(Vbf, Vtb);
  flash5<<<dim3(32,32,2), 128, 0, stream>>>(Qbf, Kbf, Vtb, O0,O1, L0,L1, 0);
  combine_ln<<<NROWS, 64, 0, stream>>>(O0,O1, L0,L1, Vf, A_n1g, A_n1b, h1p);
  gemm2<<<dim3(256,8), 256, 0, stream>>>(h1p, APLANE, 128, 128, 4, warena + 98304, 65536, oF1A, 512, 1, 1);
  gemm2<<<dim3(256,2), 256, 0, stream>>>(mid, 0,      512, 512, 16, warena + 229376, 65536, oF2A, 128, 1, 0);
  ln2<<<NROWS, 64, 0, stream>>>(h1p, ffo, A_n2g, A_n2b, vAp);

  // ---- Layer B ----
  gemm2<<<dim3(256,4), 256, 0, stream>>>(Xs, APLANE, 128, 64, 2,  warena + 360448, 16384, oQKB, 256, 2, 0);
  gemm2<<<dim3(256,2), 256, 0, stream>>>(vAp, APLANE, 128, 128, 4, warena + 393216, 16384, oVB, 128, 1, 0);
  vtrans2<<<dim3(32,32), 256, 0, stream>>>(Vbf, Vtb);
  flash5<<<dim3(32,32,2), 128, 0, stream>>>(Qbf, Kbf, Vtb, O0,O1, L0,L1, 1);
  combine_b<<<NROWS*128/256, 256, 0, stream>>>(O0,O1, L0,L1, h1p);
  gemm2<<<dim3(256,8), 256, 0, stream>>>(h1p, APLANE, 128, 128, 4, warena + 425984, 65536, oF1B, 512, 1, 1);
  out2<<<NROWS/8, 256, 0, stream>>>(mid, Wc, bc, out);
}